// Round 4
// baseline (235.421 us; speedup 1.0000x reference)
//
#include <hip/hip_runtime.h>

#define T_TOK  16384
#define IN_F   1024
#define OUT_F  1024
#define NE     8

typedef __bf16 bf16;
typedef bf16  bf16x4 __attribute__((ext_vector_type(4)));
typedef bf16  bf16x8 __attribute__((ext_vector_type(8)));
typedef float f32x4  __attribute__((ext_vector_type(4)));

// ---------------------------------------------------------------------------
// Pass 1: fp32 -> bf16 convert of x and W into workspace + zero-fill out
// (out must be 0 before the stream-K GEMM's atomic flushes).
// ---------------------------------------------------------------------------
#define CVT_THREADS 256
#define NX_CHUNKS (T_TOK * IN_F / 4)
#define NW_CHUNKS (NE * OUT_F * IN_F / 4)
#define NO_CHUNKS (T_TOK * OUT_F / 4)
#define NCVT_CHUNKS (NX_CHUNKS + NW_CHUNKS)
#define NALL_CHUNKS (NCVT_CHUNKS + NO_CHUNKS)

__global__ __launch_bounds__(CVT_THREADS)
void cvt_and_zero(const float* __restrict__ x, const float* __restrict__ w,
                  bf16* __restrict__ xb, bf16* __restrict__ wb,
                  float* __restrict__ out)
{
    for (int i = blockIdx.x * CVT_THREADS + threadIdx.x; i < NALL_CHUNKS;
         i += gridDim.x * CVT_THREADS) {
        if (i < NCVT_CHUNKS) {
            const bool isx = (i < NX_CHUNKS);
            const int  j   = isx ? i : i - NX_CHUNKS;
            f32x4 v = isx ? ((const f32x4*)x)[j] : ((const f32x4*)w)[j];
            bf16x4 h;
            #pragma unroll
            for (int k = 0; k < 4; ++k) h[k] = (bf16)v[k];
            if (isx) ((bf16x4*)xb)[j] = h;
            else     ((bf16x4*)wb)[j] = h;
        } else {
            f32x4 z = {0.f, 0.f, 0.f, 0.f};
            ((f32x4*)out)[i - NCVT_CHUNKS] = z;
        }
    }
}

// ---------------------------------------------------------------------------
// Pass 2: stream-K grouped GEMM. 256x256 tile, BK=64, 8 waves, 2-phase dbuf
// (unchanged inner loop from r3 — measured 2.75 TF/CU = ~700 TF machine rate).
// NEW: persistent 256-block grid; work unit = (tile, K-chunk of 64); every
// block gets an exactly-equal contiguous unit range -> no tail quantization
// (r3 lost 2x to 272 tiles over 256 CUs). Partial-K pieces flush with HW
// f32 atomics onto pre-zeroed out; full-K pieces plain-store.
// ---------------------------------------------------------------------------
#define BM 256
#define BN 256
#define BK 64
#define GTHREADS 512
#define NBLOCKS 256
#define KCH (IN_F / BK)      // 16 K-chunks per tile

__device__ __forceinline__ void gld_lds16(const bf16* g, bf16* l) {
    __builtin_amdgcn_global_load_lds(
        (const __attribute__((address_space(1))) void*)g,
        (__attribute__((address_space(3))) void*)l,
        16, 0, 0);
}

__global__ __launch_bounds__(GTHREADS)
void grouped_gemm_streamk(const bf16* __restrict__ xb,
                          const bf16* __restrict__ wb,
                          const int*  __restrict__ seg_lens,
                          float* __restrict__ out)
{
    __shared__ __align__(16) bf16 As[2][BM * BK];   // 2 x 32 KiB
    __shared__ __align__(16) bf16 Bs[2][BN * BK];   // 2 x 32 KiB

    const int tid  = threadIdx.x;
    const int lane = tid & 63;
    const int wave = tid >> 6;
    const int wr   = wave >> 2;          // 0..1 : 128-row half
    const int wc   = wave & 3;           // 0..3 : 64-col quarter
    const int quad = lane >> 4;
    const int l16  = lane & 15;
    const int rq   = lane >> 3;          // staging: row-in-issue
    const int ke   = (lane & 7) * 8;     // staging: k-elem offset
    const int q0   = wave * 4;

    // ---- cache segment lengths; compute unit range for this block ----
    int sl[NE];
    #pragma unroll
    for (int e = 0; e < NE; ++e) sl[e] = seg_lens[e];

    int n_slots = 0;
    #pragma unroll
    for (int e = 0; e < NE; ++e) n_slots += (sl[e] + BM - 1) >> 8;

    const int L    = n_slots * (OUT_F / BN);   // total tiles
    const int U    = L * KCH;                  // total K-chunk units
    const int base = U >> 8;                   // U / 256
    const int rem  = U & 255;
    const int b    = blockIdx.x;
    int u          = b * base + (b < rem ? b : rem);
    const int uend = u + base + (b < rem ? 1 : 0);

    while (u < uend) {
        // ---- piece: contiguous K-chunks [kc0, kc1) of one tile ----
        const int tile = u >> 4;
        const int kc0  = u & (KCH - 1);
        int kc1 = kc0 + (uend - u);
        if (kc1 > KCH) kc1 = KCH;
        u += kc1 - kc0;

        const int slot = tile >> 2;
        const int col0 = (tile & 3) << 8;

        // ---- slot -> (expert, row0, rows), 256-row granularity ----
        int e_sel = -1, row0 = 0, rows = 0;
        {
            int start = 0, acct = 0;
            #pragma unroll
            for (int e = 0; e < NE; ++e) {
                int len = sl[e];
                int nt  = (len + BM - 1) >> 8;
                if (e_sel < 0 && slot >= acct && slot < acct + nt) {
                    e_sel = e;
                    row0  = start + (slot - acct) * BM;
                    int rm = start + len - row0;
                    rows = rm < BM ? rm : BM;
                }
                acct  += nt;
                start += len;
            }
        }

        const bf16* wbase = wb + ((size_t)e_sel * OUT_F + (size_t)col0) * IN_F;

        // ---- staging pointers: 32 KiB tile = 32 wave-issues of 1 KiB ----
        const bf16* ga[4];
        const bf16* gb[4];
        #pragma unroll
        for (int i = 0; i < 4; ++i) {
            int q  = wave * 4 + i;
            int ra = row0 + q * 8 + rq;
            if (ra > T_TOK - 1) ra = T_TOK - 1;   // clamp partial last tile
            ga[i] = xb + (size_t)ra * IN_F + ke;
            gb[i] = wbase + (size_t)(q * 8 + rq) * IN_F + ke;
        }

        f32x4 acc[8][4] = {};

        // ---- prologue: stage K-chunk kc0 into buffer 0 ----
        {
            const int kb = kc0 * BK;
            #pragma unroll
            for (int i = 0; i < 4; ++i) {
                gld_lds16(ga[i] + kb, &As[0][(q0 + i) * 512]);
                gld_lds16(gb[i] + kb, &Bs[0][(q0 + i) * 512]);
            }
        }
        __syncthreads();

        int cur = 0;
        for (int ks = kc0; ks < kc1; ++ks) {
            const int kn = (ks + 1) * BK;
            if (ks + 1 < kc1) {       // prefetch next chunk into alt buffer
                #pragma unroll
                for (int i = 0; i < 4; ++i) {
                    gld_lds16(ga[i] + kn, &As[cur ^ 1][(q0 + i) * 512]);
                    gld_lds16(gb[i] + kn, &Bs[cur ^ 1][(q0 + i) * 512]);
                }
            }

            #pragma unroll
            for (int kk = 0; kk < 2; ++kk) {
                bf16x8 af[8], bfr[4];
                #pragma unroll
                for (int t = 0; t < 8; ++t)
                    af[t] = *(const bf16x8*)(
                        &As[cur][(wr * 128 + t * 16 + l16) * BK + kk * 32 + quad * 8]);
                #pragma unroll
                for (int v = 0; v < 4; ++v)
                    bfr[v] = *(const bf16x8*)(
                        &Bs[cur][(wc * 64 + v * 16 + l16) * BK + kk * 32 + quad * 8]);
                #pragma unroll
                for (int t = 0; t < 8; ++t)
                    #pragma unroll
                    for (int v = 0; v < 4; ++v)
                        acc[t][v] = __builtin_amdgcn_mfma_f32_16x16x32_bf16(
                            af[t], bfr[v], acc[t][v], 0, 0, 0);
            }

            __syncthreads();   // drains prefetch vmcnt + this chunk's ds_reads
            cur ^= 1;
        }

        // ---- flush piece. C/D layout: col=lane&15, row=quad*4+reg ----
        if (kc0 == 0 && kc1 == KCH) {
            // sole contributor: plain store
            #pragma unroll
            for (int t = 0; t < 8; ++t) {
                #pragma unroll
                for (int r = 0; r < 4; ++r) {
                    int row = wr * 128 + t * 16 + quad * 4 + r;
                    if (row < rows) {
                        size_t ob = (size_t)(row0 + row) * OUT_F + col0 + wc * 64;
                        #pragma unroll
                        for (int v = 0; v < 4; ++v)
                            out[ob + v * 16 + l16] = acc[t][v][r];
                    }
                }
            }
        } else {
            // split tile: HW f32 atomic add onto pre-zeroed out
            #pragma unroll
            for (int t = 0; t < 8; ++t) {
                #pragma unroll
                for (int r = 0; r < 4; ++r) {
                    int row = wr * 128 + t * 16 + quad * 4 + r;
                    if (row < rows) {
                        size_t ob = (size_t)(row0 + row) * OUT_F + col0 + wc * 64;
                        #pragma unroll
                        for (int v = 0; v < 4; ++v)
                            unsafeAtomicAdd(&out[ob + v * 16 + l16], acc[t][v][r]);
                    }
                }
            }
        }
        // no barrier needed here: flush touches no LDS; next piece's staging
        // targets buffers whose last readers already passed the final
        // __syncthreads of this piece's K-loop.
    }
}

// ---------------------------------------------------------------------------
// Fallback (ws too small): round-0 kernel — fp32 loads, in-loop cvt.
// ---------------------------------------------------------------------------
#define FBM 128
#define FBK 32
#define FTHREADS 256
#define FROW_SLOTS 136

__global__ __launch_bounds__(FTHREADS)
void grouped_gemm_f32io_bf16(const float* __restrict__ x,
                             const float* __restrict__ wgt,
                             const int*  __restrict__ seg_lens,
                             float* __restrict__ out)
{
    __shared__ __align__(16) bf16 Asf[FBM * FBK];
    __shared__ __align__(16) bf16 Bsf[FBM * FBK];

    const int m    = blockIdx.y;
    const int col0 = blockIdx.x * FBM;

    int e_sel = -1, row0 = 0, rows = 0;
    {
        int start = 0, acct = 0;
        #pragma unroll
        for (int e = 0; e < NE; ++e) {
            int len = seg_lens[e];
            int nt  = (len + FBM - 1) >> 7;
            if (e_sel < 0 && m >= acct && m < acct + nt) {
                e_sel = e;
                row0  = start + (m - acct) * FBM;
                int rem = start + len - row0;
                rows = rem < FBM ? rem : FBM;
            }
            acct  += nt;
            start += len;
        }
    }
    if (e_sel < 0) return;

    const int tid  = threadIdx.x;
    const int lane = tid & 63;
    const int wave = tid >> 6;
    const int wm   = (wave >> 1) * 64;
    const int wn   = (wave & 1) * 64;
    const int quad = lane >> 4;
    const int l16  = lane & 15;

    const float* wbase = wgt + ((size_t)e_sel * OUT_F + (size_t)col0) * IN_F;

    f32x4 acc[4][4] = {};

    for (int k0 = 0; k0 < IN_F; k0 += FBK) {
        f32x4 a_st[4], b_st[4];
        #pragma unroll
        for (int t = 0; t < 4; ++t) {
            int c  = t * FTHREADS + tid;
            int rg = row0 + (c >> 3);
            if (rg > T_TOK - 1) rg = T_TOK - 1;
            a_st[t] = *(const f32x4*)(x + (size_t)rg * IN_F + k0 + (c & 7) * 4);
            b_st[t] = *(const f32x4*)(wbase + (size_t)(c >> 3) * IN_F + k0 + (c & 7) * 4);
        }

        __syncthreads();

        #pragma unroll
        for (int t = 0; t < 4; ++t) {
            int c = t * FTHREADS + tid;
            bf16x4 ha, hb;
            #pragma unroll
            for (int j = 0; j < 4; ++j) { ha[j] = (bf16)a_st[t][j]; hb[j] = (bf16)b_st[t][j]; }
            *(bf16x4*)(&Asf[(c >> 3) * FBK + (c & 7) * 4]) = ha;
            *(bf16x4*)(&Bsf[(c >> 3) * FBK + (c & 7) * 4]) = hb;
        }
        __syncthreads();

        bf16x8 af[4], bfr[4];
        #pragma unroll
        for (int t = 0; t < 4; ++t)
            af[t] = *(const bf16x8*)(&Asf[(wm + t * 16 + l16) * FBK + quad * 8]);
        #pragma unroll
        for (int v = 0; v < 4; ++v)
            bfr[v] = *(const bf16x8*)(&Bsf[(wn + v * 16 + l16) * FBK + quad * 8]);

        #pragma unroll
        for (int t = 0; t < 4; ++t)
            #pragma unroll
            for (int v = 0; v < 4; ++v)
                acc[t][v] = __builtin_amdgcn_mfma_f32_16x16x32_bf16(
                    af[t], bfr[v], acc[t][v], 0, 0, 0);
    }

    #pragma unroll
    for (int t = 0; t < 4; ++t) {
        #pragma unroll
        for (int r = 0; r < 4; ++r) {
            int row = wm + t * 16 + quad * 4 + r;
            if (row < rows) {
                size_t ob = (size_t)(row0 + row) * OUT_F + col0;
                #pragma unroll
                for (int v = 0; v < 4; ++v)
                    out[ob + wn + v * 16 + l16] = acc[t][v][r];
            }
        }
    }
}

extern "C" void kernel_launch(void* const* d_in, const int* in_sizes, int n_in,
                              void* d_out, int out_size, void* d_ws, size_t ws_size,
                              hipStream_t stream) {
    const float* x   = (const float*)d_in[0];
    const float* wgt = (const float*)d_in[1];
    const int*   seg = (const int*)d_in[2];
    float* out = (float*)d_out;

    const size_t xbytes = (size_t)T_TOK * IN_F * sizeof(bf16);       // 33.55 MB
    const size_t wbytes = (size_t)NE * OUT_F * IN_F * sizeof(bf16);  // 16.78 MB

    if (ws_size >= xbytes + wbytes) {
        bf16* xb = (bf16*)d_ws;
        bf16* wb = (bf16*)((char*)d_ws + xbytes);
        cvt_and_zero<<<dim3(2048, 1, 1), dim3(CVT_THREADS, 1, 1), 0, stream>>>(
            x, wgt, xb, wb, out);
        grouped_gemm_streamk<<<dim3(NBLOCKS, 1, 1), dim3(GTHREADS, 1, 1), 0, stream>>>(
            xb, wb, seg, out);
    } else {
        grouped_gemm_f32io_bf16<<<dim3(OUT_F / FBM, FROW_SLOTS, 1),
                                  dim3(FTHREADS, 1, 1), 0, stream>>>(x, wgt, seg, out);
    }
}

// Round 5
// 224.812 us; speedup vs baseline: 1.0472x; 1.0472x over previous
//
#include <hip/hip_runtime.h>

#define T_TOK  16384
#define IN_F   1024
#define OUT_F  1024
#define NE     8

typedef __bf16 bf16;
typedef bf16  bf16x4 __attribute__((ext_vector_type(4)));
typedef bf16  bf16x8 __attribute__((ext_vector_type(8)));
typedef float f32x4  __attribute__((ext_vector_type(4)));

// ---------------------------------------------------------------------------
// Pass 1: fp32 -> bf16 convert of x and W into workspace + zero-fill out
// (surplus-tile atomic flushes in pass 2 need out pre-zeroed).
// ---------------------------------------------------------------------------
#define CVT_THREADS 256
#define NX_CHUNKS (T_TOK * IN_F / 4)
#define NW_CHUNKS (NE * OUT_F * IN_F / 4)
#define NO_CHUNKS (T_TOK * OUT_F / 4)
#define NCVT_CHUNKS (NX_CHUNKS + NW_CHUNKS)
#define NALL_CHUNKS (NCVT_CHUNKS + NO_CHUNKS)

__global__ __launch_bounds__(CVT_THREADS)
void cvt_and_zero(const float* __restrict__ x, const float* __restrict__ w,
                  bf16* __restrict__ xb, bf16* __restrict__ wb,
                  float* __restrict__ out)
{
    for (int i = blockIdx.x * CVT_THREADS + threadIdx.x; i < NALL_CHUNKS;
         i += gridDim.x * CVT_THREADS) {
        if (i < NCVT_CHUNKS) {
            const bool isx = (i < NX_CHUNKS);
            const int  j   = isx ? i : i - NX_CHUNKS;
            f32x4 v = isx ? ((const f32x4*)x)[j] : ((const f32x4*)w)[j];
            bf16x4 h;
            #pragma unroll
            for (int k = 0; k < 4; ++k) h[k] = (bf16)v[k];
            if (isx) ((bf16x4*)xb)[j] = h;
            else     ((bf16x4*)wb)[j] = h;
        } else {
            f32x4 z = {0.f, 0.f, 0.f, 0.f};
            ((f32x4*)out)[i - NCVT_CHUNKS] = z;
        }
    }
}

// ---------------------------------------------------------------------------
// Pass 2: HYBRID grouped GEMM. 256x256 tile, BK=64, 8 waves, 2-phase dbuf.
//  - Blocks 0..255: ONE full tile each, compile-time-unrolled K-loop
//    (r3-verbatim hot path; measured ~2.75 TF/CU).
//  - Surplus tiles (L-256 <= 28, ~6% of work): K-chunk units spread <=2
//    per block via the runtime unit loop; atomic flush onto zeroed out.
// Main stores and surplus atomics touch disjoint tiles.
// ---------------------------------------------------------------------------
#define BM 256
#define BN 256
#define BK 64
#define GTHREADS 512
#define NBLOCKS 256
#define KCH (IN_F / BK)      // 16 K-chunks per tile

__device__ __forceinline__ void gld_lds16(const bf16* g, bf16* l) {
    __builtin_amdgcn_global_load_lds(
        (const __attribute__((address_space(1))) void*)g,
        (__attribute__((address_space(3))) void*)l,
        16, 0, 0);
}

__device__ __forceinline__ void resolve_slot(const int* sl, int slot,
                                             int& e_sel, int& row0, int& rows)
{
    e_sel = -1; row0 = 0; rows = 0;
    int start = 0, acct = 0;
    #pragma unroll
    for (int e = 0; e < NE; ++e) {
        int len = sl[e];
        int nt  = (len + BM - 1) >> 8;
        if (e_sel < 0 && slot >= acct && slot < acct + nt) {
            e_sel = e;
            row0  = start + (slot - acct) * BM;
            int rm = start + len - row0;
            rows = rm < BM ? rm : BM;
        }
        acct  += nt;
        start += len;
    }
}

__global__ __launch_bounds__(GTHREADS)
void grouped_gemm_hybrid(const bf16* __restrict__ xb,
                         const bf16* __restrict__ wb,
                         const int*  __restrict__ seg_lens,
                         float* __restrict__ out)
{
    __shared__ __align__(16) bf16 As[2][BM * BK];   // 2 x 32 KiB
    __shared__ __align__(16) bf16 Bs[2][BN * BK];   // 2 x 32 KiB

    const int tid  = threadIdx.x;
    const int lane = tid & 63;
    const int wave = tid >> 6;
    const int wr   = wave >> 2;          // 0..1 : 128-row half
    const int wc   = wave & 3;           // 0..3 : 64-col quarter
    const int quad = lane >> 4;
    const int l16  = lane & 15;
    const int rq   = lane >> 3;          // staging: row-in-issue
    const int ke   = (lane & 7) * 8;     // staging: k-elem offset
    const int q0   = wave * 4;
    const int b    = blockIdx.x;

    int sl[NE];
    #pragma unroll
    for (int e = 0; e < NE; ++e) sl[e] = seg_lens[e];

    int n_slots = 0;
    #pragma unroll
    for (int e = 0; e < NE; ++e) n_slots += (sl[e] + BM - 1) >> 8;
    const int L = n_slots * (OUT_F / BN);   // total tiles (>= 256 since sum=16384)

    // ======================= main tile: tile index = b =======================
    if (b < L) {
        const int slot = b >> 2;
        const int col0 = (b & 3) << 8;
        int e_sel, row0, rows;
        resolve_slot(sl, slot, e_sel, row0, rows);

        const bf16* wbase = wb + ((size_t)e_sel * OUT_F + (size_t)col0) * IN_F;

        const bf16* ga[4];
        const bf16* gb[4];
        #pragma unroll
        for (int i = 0; i < 4; ++i) {
            int q  = wave * 4 + i;
            int ra = row0 + q * 8 + rq;
            if (ra > T_TOK - 1) ra = T_TOK - 1;
            ga[i] = xb + (size_t)ra * IN_F + ke;
            gb[i] = wbase + (size_t)(q * 8 + rq) * IN_F + ke;
        }

        f32x4 acc[8][4] = {};

        // prologue: stage K-tile 0 into buffer 0
        #pragma unroll
        for (int i = 0; i < 4; ++i) {
            gld_lds16(ga[i], &As[0][(q0 + i) * 512]);
            gld_lds16(gb[i], &Bs[0][(q0 + i) * 512]);
        }
        __syncthreads();

        int cur = 0;
        #pragma unroll
        for (int ks = 0; ks < KCH; ++ks) {
            const int kn = (ks + 1) * BK;
            if (ks + 1 < KCH) {   // compile-time resolved per unrolled iter
                #pragma unroll
                for (int i = 0; i < 4; ++i) {
                    gld_lds16(ga[i] + kn, &As[cur ^ 1][(q0 + i) * 512]);
                    gld_lds16(gb[i] + kn, &Bs[cur ^ 1][(q0 + i) * 512]);
                }
            }

            #pragma unroll
            for (int kk = 0; kk < 2; ++kk) {
                bf16x8 af[8], bfr[4];
                #pragma unroll
                for (int t = 0; t < 8; ++t)
                    af[t] = *(const bf16x8*)(
                        &As[cur][(wr * 128 + t * 16 + l16) * BK + kk * 32 + quad * 8]);
                #pragma unroll
                for (int v = 0; v < 4; ++v)
                    bfr[v] = *(const bf16x8*)(
                        &Bs[cur][(wc * 64 + v * 16 + l16) * BK + kk * 32 + quad * 8]);
                #pragma unroll
                for (int t = 0; t < 8; ++t)
                    #pragma unroll
                    for (int v = 0; v < 4; ++v)
                        acc[t][v] = __builtin_amdgcn_mfma_f32_16x16x32_bf16(
                            af[t], bfr[v], acc[t][v], 0, 0, 0);
            }

            __syncthreads();
            cur ^= 1;
        }

        // epilogue: plain store (sole contributor of this tile)
        #pragma unroll
        for (int t = 0; t < 8; ++t) {
            #pragma unroll
            for (int r = 0; r < 4; ++r) {
                int row = wr * 128 + t * 16 + quad * 4 + r;
                if (row < rows) {
                    size_t ob = (size_t)(row0 + row) * OUT_F + col0 + wc * 64;
                    #pragma unroll
                    for (int v = 0; v < 4; ++v)
                        out[ob + v * 16 + l16] = acc[t][v][r];
                }
            }
        }
    }

    // ================= surplus tiles [NBLOCKS, L): stream-K units ============
    const int Uleft = (L - NBLOCKS) * KCH;
    if (Uleft <= 0) return;
    {
        const int base = Uleft >> 8;
        const int rem  = Uleft & 255;
        int u    = NBLOCKS * KCH + b * base + (b < rem ? b : rem);
        int uend = u + base + (b < rem ? 1 : 0);

        while (u < uend) {
            const int tile = u >> 4;
            const int kc0  = u & (KCH - 1);
            int kc1 = kc0 + (uend - u);
            if (kc1 > KCH) kc1 = KCH;
            u += kc1 - kc0;

            const int slot = tile >> 2;
            const int col0 = (tile & 3) << 8;
            int e_sel, row0, rows;
            resolve_slot(sl, slot, e_sel, row0, rows);

            const bf16* wbase = wb + ((size_t)e_sel * OUT_F + (size_t)col0) * IN_F;

            const bf16* ga[4];
            const bf16* gb[4];
            #pragma unroll
            for (int i = 0; i < 4; ++i) {
                int q  = wave * 4 + i;
                int ra = row0 + q * 8 + rq;
                if (ra > T_TOK - 1) ra = T_TOK - 1;
                ga[i] = xb + (size_t)ra * IN_F + ke;
                gb[i] = wbase + (size_t)(q * 8 + rq) * IN_F + ke;
            }

            f32x4 acc[8][4] = {};

            {
                const int kb = kc0 * BK;
                #pragma unroll
                for (int i = 0; i < 4; ++i) {
                    gld_lds16(ga[i] + kb, &As[0][(q0 + i) * 512]);
                    gld_lds16(gb[i] + kb, &Bs[0][(q0 + i) * 512]);
                }
            }
            __syncthreads();

            int cur = 0;
            for (int ks = kc0; ks < kc1; ++ks) {
                const int kn = (ks + 1) * BK;
                if (ks + 1 < kc1) {
                    #pragma unroll
                    for (int i = 0; i < 4; ++i) {
                        gld_lds16(ga[i] + kn, &As[cur ^ 1][(q0 + i) * 512]);
                        gld_lds16(gb[i] + kn, &Bs[cur ^ 1][(q0 + i) * 512]);
                    }
                }

                #pragma unroll
                for (int kk = 0; kk < 2; ++kk) {
                    bf16x8 af[8], bfr[4];
                    #pragma unroll
                    for (int t = 0; t < 8; ++t)
                        af[t] = *(const bf16x8*)(
                            &As[cur][(wr * 128 + t * 16 + l16) * BK + kk * 32 + quad * 8]);
                    #pragma unroll
                    for (int v = 0; v < 4; ++v)
                        bfr[v] = *(const bf16x8*)(
                            &Bs[cur][(wc * 64 + v * 16 + l16) * BK + kk * 32 + quad * 8]);
                    #pragma unroll
                    for (int t = 0; t < 8; ++t)
                        #pragma unroll
                        for (int v = 0; v < 4; ++v)
                            acc[t][v] = __builtin_amdgcn_mfma_f32_16x16x32_bf16(
                                af[t], bfr[v], acc[t][v], 0, 0, 0);
                }

                __syncthreads();
                cur ^= 1;
            }

            // atomic flush onto pre-zeroed out (tile may have other contributors)
            #pragma unroll
            for (int t = 0; t < 8; ++t) {
                #pragma unroll
                for (int r = 0; r < 4; ++r) {
                    int row = wr * 128 + t * 16 + quad * 4 + r;
                    if (row < rows) {
                        size_t ob = (size_t)(row0 + row) * OUT_F + col0 + wc * 64;
                        #pragma unroll
                        for (int v = 0; v < 4; ++v)
                            unsafeAtomicAdd(&out[ob + v * 16 + l16], acc[t][v][r]);
                    }
                }
            }
        }
    }
}

// ---------------------------------------------------------------------------
// Fallback (ws too small): round-0 kernel — fp32 loads, in-loop cvt.
// ---------------------------------------------------------------------------
#define FBM 128
#define FBK 32
#define FTHREADS 256
#define FROW_SLOTS 136

__global__ __launch_bounds__(FTHREADS)
void grouped_gemm_f32io_bf16(const float* __restrict__ x,
                             const float* __restrict__ wgt,
                             const int*  __restrict__ seg_lens,
                             float* __restrict__ out)
{
    __shared__ __align__(16) bf16 Asf[FBM * FBK];
    __shared__ __align__(16) bf16 Bsf[FBM * FBK];

    const int m    = blockIdx.y;
    const int col0 = blockIdx.x * FBM;

    int e_sel = -1, row0 = 0, rows = 0;
    {
        int start = 0, acct = 0;
        #pragma unroll
        for (int e = 0; e < NE; ++e) {
            int len = seg_lens[e];
            int nt  = (len + FBM - 1) >> 7;
            if (e_sel < 0 && m >= acct && m < acct + nt) {
                e_sel = e;
                row0  = start + (m - acct) * FBM;
                int rem = start + len - row0;
                rows = rem < FBM ? rem : FBM;
            }
            acct  += nt;
            start += len;
        }
    }
    if (e_sel < 0) return;

    const int tid  = threadIdx.x;
    const int lane = tid & 63;
    const int wave = tid >> 6;
    const int wm   = (wave >> 1) * 64;
    const int wn   = (wave & 1) * 64;
    const int quad = lane >> 4;
    const int l16  = lane & 15;

    const float* wbase = wgt + ((size_t)e_sel * OUT_F + (size_t)col0) * IN_F;

    f32x4 acc[4][4] = {};

    for (int k0 = 0; k0 < IN_F; k0 += FBK) {
        f32x4 a_st[4], b_st[4];
        #pragma unroll
        for (int t = 0; t < 4; ++t) {
            int c  = t * FTHREADS + tid;
            int rg = row0 + (c >> 3);
            if (rg > T_TOK - 1) rg = T_TOK - 1;
            a_st[t] = *(const f32x4*)(x + (size_t)rg * IN_F + k0 + (c & 7) * 4);
            b_st[t] = *(const f32x4*)(wbase + (size_t)(c >> 3) * IN_F + k0 + (c & 7) * 4);
        }

        __syncthreads();

        #pragma unroll
        for (int t = 0; t < 4; ++t) {
            int c = t * FTHREADS + tid;
            bf16x4 ha, hb;
            #pragma unroll
            for (int j = 0; j < 4; ++j) { ha[j] = (bf16)a_st[t][j]; hb[j] = (bf16)b_st[t][j]; }
            *(bf16x4*)(&Asf[(c >> 3) * FBK + (c & 7) * 4]) = ha;
            *(bf16x4*)(&Bsf[(c >> 3) * FBK + (c & 7) * 4]) = hb;
        }
        __syncthreads();

        bf16x8 af[4], bfr[4];
        #pragma unroll
        for (int t = 0; t < 4; ++t)
            af[t] = *(const bf16x8*)(&Asf[(wm + t * 16 + l16) * FBK + quad * 8]);
        #pragma unroll
        for (int v = 0; v < 4; ++v)
            bfr[v] = *(const bf16x8*)(&Bsf[(wn + v * 16 + l16) * FBK + quad * 8]);

        #pragma unroll
        for (int t = 0; t < 4; ++t)
            #pragma unroll
            for (int v = 0; v < 4; ++v)
                acc[t][v] = __builtin_amdgcn_mfma_f32_16x16x32_bf16(
                    af[t], bfr[v], acc[t][v], 0, 0, 0);
    }

    #pragma unroll
    for (int t = 0; t < 4; ++t) {
        #pragma unroll
        for (int r = 0; r < 4; ++r) {
            int row = wm + t * 16 + quad * 4 + r;
            if (row < rows) {
                size_t ob = (size_t)(row0 + row) * OUT_F + col0;
                #pragma unroll
                for (int v = 0; v < 4; ++v)
                    out[ob + wn + v * 16 + l16] = acc[t][v][r];
            }
        }
    }
}

extern "C" void kernel_launch(void* const* d_in, const int* in_sizes, int n_in,
                              void* d_out, int out_size, void* d_ws, size_t ws_size,
                              hipStream_t stream) {
    const float* x   = (const float*)d_in[0];
    const float* wgt = (const float*)d_in[1];
    const int*   seg = (const int*)d_in[2];
    float* out = (float*)d_out;

    const size_t xbytes = (size_t)T_TOK * IN_F * sizeof(bf16);       // 33.55 MB
    const size_t wbytes = (size_t)NE * OUT_F * IN_F * sizeof(bf16);  // 16.78 MB

    if (ws_size >= xbytes + wbytes) {
        bf16* xb = (bf16*)d_ws;
        bf16* wb = (bf16*)((char*)d_ws + xbytes);
        cvt_and_zero<<<dim3(2048, 1, 1), dim3(CVT_THREADS, 1, 1), 0, stream>>>(
            x, wgt, xb, wb, out);
        grouped_gemm_hybrid<<<dim3(NBLOCKS, 1, 1), dim3(GTHREADS, 1, 1), 0, stream>>>(
            xb, wb, seg, out);
    } else {
        grouped_gemm_f32io_bf16<<<dim3(OUT_F / FBM, FROW_SLOTS, 1),
                                  dim3(FTHREADS, 1, 1), 0, stream>>>(x, wgt, seg, out);
    }
}